// Round 5
// baseline (344.058 us; speedup 1.0000x reference)
//
#include <hip/hip_runtime.h>
#include <hip/hip_bf16.h>

#define DEV_INLINE __device__ __forceinline__

typedef __bf16 bf16x8 __attribute__((ext_vector_type(8)));
typedef float  floatx4 __attribute__((ext_vector_type(4)));
typedef short  shortx2 __attribute__((ext_vector_type(2)));

DEV_INLINE bf16x8 ld_frag(const __bf16* p) {
    union { uint4 u; bf16x8 v; } t;
    t.u = *(const uint4*)p;
    return t.v;
}
// cvt-first relu+pack: convert two f32x4 accs to bf16, then clamp negatives
// via packed i16 max (sign-bit test == float x>0 test; exact vs fmax-then-cvt
// for all finite inputs). Element j = relu(acc[2kq + (j>>2)][j&3]).
DEV_INLINE bf16x8 pack_relu2(floatx4 a, floatx4 b) {
    union { __hip_bfloat162 h[4]; shortx2 s[4]; bf16x8 v; } t;
    t.h[0] = __float22bfloat162_rn({a[0], a[1]});
    t.h[1] = __float22bfloat162_rn({a[2], a[3]});
    t.h[2] = __float22bfloat162_rn({b[0], b[1]});
    t.h[3] = __float22bfloat162_rn({b[2], b[3]});
    const shortx2 z = {0, 0};
#pragma unroll
    for (int i = 0; i < 4; ++i) t.s[i] = __builtin_elementwise_max(t.s[i], z);
    return t.v;
}
DEV_INLINE floatx4 vmax4(floatx4 a, floatx4 b) {
    floatx4 r;
#pragma unroll
    for (int i = 0; i < 4; ++i) r[i] = fmaxf(a[i], b[i]);
    return r;
}

// ---------------------------------------------------------------------------
// Prep. tp: natural transpose+pad (A-layout [n][k]). tp_b: same, with the
// bias placed in padded row k==Ks (consumer sets x[k=Ks]=1.0). tp_perm:
// k-permuted so the consumer uses the previous layer's accumulators directly.
// ---------------------------------------------------------------------------
template<int N, int Kp, int Ks>
DEV_INLINE void tp(__bf16* dst, const float* __restrict__ src, int idx0, int stride) {
    for (int e = idx0; e < N * Kp; e += stride) {
        int n = e / Kp, k = e - n * Kp;
        dst[e] = (k < Ks) ? (__bf16)src[k * N + n] : (__bf16)0.0f;
    }
}
template<int N, int Kp, int Ks>
DEV_INLINE void tp_b(__bf16* dst, const float* __restrict__ src,
                     const float* __restrict__ bias, int idx0, int stride) {
    for (int e = idx0; e < N * Kp; e += stride) {
        int n = e / Kp, k = e - n * Kp;
        float v = (k < Ks) ? src[k * N + n] : ((k == Ks) ? bias[n] : 0.0f);
        dst[e] = (__bf16)v;
    }
}
template<int N, int K>   // dst[n][k_hw] = src[c(k_hw)][n]
DEV_INLINE void tp_perm(__bf16* dst, const float* __restrict__ src, int idx0, int stride) {
    for (int e = idx0; e < N * K; e += stride) {
        int n = e / K, kh = e - n * K;
        int qd = (kh >> 3) & 3, kq = kh >> 5, j = kh & 7;
        int c = (2 * kq + (j >> 2)) * 16 + qd * 4 + (j & 3);
        dst[e] = (__bf16)src[c * N + n];
    }
}

__global__ __launch_bounds__(256)
void prep_kernel(const float* __restrict__ rw1, const float* __restrict__ rb1,
                 const float* __restrict__ rw2, const float* __restrict__ rw3,
                 const float* __restrict__ tw1, const float* __restrict__ tb1,
                 const float* __restrict__ tw2, const float* __restrict__ tw3,
                 const float* __restrict__ mw1, const float* __restrict__ mw2,
                 const float* __restrict__ mw3, __bf16* __restrict__ wb)
{
    int i0 = blockIdx.x * 256 + threadIdx.x;
    int st = gridDim.x * 256;
    tp_b   < 64,  32,   6>(wb + 0,     rw1, rb1, i0, st);
    tp_perm< 64,  64>     (wb + 2048,  rw2, i0, st);
    tp_perm< 32,  64>     (wb + 6144,  rw3, i0, st);
    tp_b   < 64,  32,   7>(wb + 8192,  tw1, tb1, i0, st);
    tp_perm< 64,  64>     (wb + 10240, tw2, i0, st);
    tp_perm< 32,  64>     (wb + 14336, tw3, i0, st);
    tp     <128, 128, 108>(wb + 16384, mw1, i0, st);
    tp_perm<128, 128>     (wb + 32768, mw2, i0, st);
    tp_perm< 64, 128>     (wb + 49152, mw3, i0, st);
}

// ---------------------------------------------------------------------------
// Persistent fused encoder, R12: w1 frags in registers (+16 VGPR, base 36);
// w2/w3 in LDS in LANE-MAJOR frag order (chunk = (mt*2+kq)*64 + l64) so every
// ds_read_b128 is a contiguous 1024B wave read (conflict-free, one base reg +
// immediate offsets). LDS 18688 B + VGPR<=64 => __launch_bounds__(256,8),
// 8 blocks/CU. Grid 4096: 2048 robot x 4 iters, 2048 track x 8 iters.
// pack_relu2 uses packed i16 max (saves 4 VALU/call).
// ---------------------------------------------------------------------------
struct __align__(16) EncSmem {
    __bf16 wt[6144];         // w2 lane-major (0..4095) | w3 (4096..6143) 12288 B
    float2 pb[2 * 128];      // wave partials (sum,max), dbuf  2048 B
    float  bs[64];           // b2                              256 B
    __bf16 xs[2][128 * 8];   // x tiles, k padded to 8         4096 B
};

template<int DIN>
DEV_INLINE void x_load(const float* __restrict__ X, int bid, int tid, float (&g)[4]) {
    const float* src = X + (size_t)bid * 128 * DIN;
#pragma unroll
    for (int p = 0; p < 4; ++p) {
        int e = tid + p * 256;
        if ((DIN == 6) ? (p < 3) : (e < 128 * 7)) g[p] = src[e];
    }
}
template<int DIN>
DEV_INLINE void x_store(__bf16* xbuf, int tid, const float (&g)[4]) {
#pragma unroll
    for (int p = 0; p < 4; ++p) {
        int e = tid + p * 256;
        if ((DIN == 6) ? (p < 3) : (e < 128 * 7)) {
            int r = e / DIN, k = e - r * DIN;
            xbuf[r * 8 + k] = (__bf16)g[p];
        }
    }
}

template<int DIN, int S, int ITERS>
DEV_INLINE void enc_loop(EncSmem& sm, const float* __restrict__ X,
                         const __bf16* __restrict__ wsrc,
                         const float* __restrict__ b2, const float* __restrict__ b3,
                         __bf16* __restrict__ out, int bid0)
{
    constexpr int NB = 128 / S;          // batches per 128-row tile
    const int tid = threadIdx.x;
    const int w   = tid >> 6;
    const int l64 = tid & 63;
    const int ln  = l64 & 15;
    const int qd  = l64 >> 4;

    if (tid < 64) sm.bs[tid] = b2[tid];

    // ---- w2/w3 -> LDS, lane-major frag order (768 x 16B chunks) ----
    // src chunk cs of tensor: n = cs>>3 (row), r = cs&7; frag owner lane
    // l64 = (r&3)*16 + (n&15); dst chunk = ((n>>4)*2 + (r>>2))*64 + l64.
    for (int c = tid; c < 768; c += 256) {
        const bool isw2 = c < 512;
        const int cs = isw2 ? c : c - 512;
        uint4 v = *(const uint4*)(wsrc + (isw2 ? 2048 : 6144) + cs * 8);
        int n = cs >> 3, r = cs & 7;
        int cd = ((n >> 4) * 2 + (r >> 2)) * 64 + (r & 3) * 16 + (n & 15);
        *(uint4*)&sm.wt[(isw2 ? 0 : 4096) + cd * 8] = v;
    }

    // pad init: k in [DIN,8) of both x buffers; bias slot k==DIN gets 1.0
    {
        __bf16* xf = &sm.xs[0][0];
        if (DIN == 6) {
            union { __bf16 h[2]; uint32_t u; } c;
            c.h[0] = (__bf16)1.0f; c.h[1] = (__bf16)0.0f;
            *(uint32_t*)&xf[tid * 8 + 6] = c.u;   // rows 0..255 across both bufs
        } else {
            xf[tid * 8 + 7] = (__bf16)1.0f;
        }
    }
    // b3 folded past pooling: e-row = Wx + b3 -> 0.5*(mean+max) = 0.5*(s/S+m)+b3[f]
    const float b3f = (tid < NB * 32) ? b3[tid & 31] : 0.0f;

    // ---- w1 frags -> registers, once per block (global, L2-resident) ----
    bf16x8 w1f[4];
#pragma unroll
    for (int mt = 0; mt < 4; ++mt)
        w1f[mt] = ld_frag(&wsrc[(mt * 16 + ln) * 32 + qd * 8]);

    const __bf16* wl = &sm.wt[l64 * 8];   // lane-major base (byte l64*16)

    bf16x8 zf;
#pragma unroll
    for (int j = 0; j < 8; ++j) zf[j] = (__bf16)0.0f;
    const floatx4 z4 = {0.0f, 0.0f, 0.0f, 0.0f};

    // ---- prologue: stage x for iter 0 ----
    float g[4];
    x_load<DIN>(X, bid0, tid, g);
    x_store<DIN>(sm.xs[0], tid, g);
    __syncthreads();

    int cur = 0, pbuf = 0;
    for (int it = 0; it < ITERS; ++it) {
        const int bid = bid0 + it;
        // issue next tile's global loads early; stored late (latency hidden
        // under the whole L1->L3 compute). Writing xs[cur^1] needs no barrier:
        // its last reads were ordered by the previous iter's barrier.
        if (it + 1 < ITERS) x_load<DIN>(X, bid + 1, tid, g);

        // ---- x B-frags from LDS (16-lane contiguous 256B reads) ----
        bf16x8 xb[2];
#pragma unroll
        for (int t = 0; t < 2; ++t) {
            bf16x8 v = zf;
            if (qd == 0) {
                const int row = (2 * w + t) * 16 + ln;
                v = ld_frag(&sm.xs[cur][row * 8]);
            }
            xb[t] = v;
        }

        // ---- L1: K=32 (b1 in weight pad row, x pad=1.0), C = 0 ----
        floatx4 a1[2][4];
#pragma unroll
        for (int mt = 0; mt < 4; ++mt)
#pragma unroll
            for (int t = 0; t < 2; ++t)
                a1[t][mt] = __builtin_amdgcn_mfma_f32_16x16x32_bf16(w1f[mt], xb[t], z4, 0, 0, 0);
        bf16x8 f1[2][2];
#pragma unroll
        for (int t = 0; t < 2; ++t)
#pragma unroll
            for (int kq = 0; kq < 2; ++kq)
                f1[t][kq] = pack_relu2(a1[t][2 * kq], a1[t][2 * kq + 1]);

        // ---- L2: 64 -> 64, rolling a2 -> f2 per mt-pair (reg cap) ----
        bf16x8 f2[2][2];
#pragma unroll
        for (int pr = 0; pr < 2; ++pr) {
            floatx4 a2[2][2];
#pragma unroll
            for (int m = 0; m < 2; ++m) {
                const int mt = pr * 2 + m;
                floatx4 bv = *(const floatx4*)&sm.bs[mt * 16 + qd * 4];
                bf16x8 wf0 = ld_frag(&wl[(mt * 2 + 0) * 512]);
                bf16x8 wf1 = ld_frag(&wl[(mt * 2 + 1) * 512]);
#pragma unroll
                for (int t = 0; t < 2; ++t) {
                    floatx4 acc;
                    acc = __builtin_amdgcn_mfma_f32_16x16x32_bf16(wf0, f1[t][0], bv, 0, 0, 0);
                    acc = __builtin_amdgcn_mfma_f32_16x16x32_bf16(wf1, f1[t][1], acc, 0, 0, 0);
                    a2[t][m] = acc;
                }
            }
#pragma unroll
            for (int t = 0; t < 2; ++t)
                f2[t][pr] = pack_relu2(a2[t][0], a2[t][1]);
        }

        // ---- L3 FLIPPED: A=f2 (rows=x-rows), B=w3 (cols=features), C=0.
        // a3[t][mt][jj] = e[xrow=(2w+t)*16+qd*4+jj][feat=mt*16+ln]
        floatx4 a3[2][2];
#pragma unroll
        for (int mt = 0; mt < 2; ++mt) {
            bf16x8 wf0 = ld_frag(&wl[4096 + (mt * 2 + 0) * 512]);
            bf16x8 wf1 = ld_frag(&wl[4096 + (mt * 2 + 1) * 512]);
#pragma unroll
            for (int t = 0; t < 2; ++t) {
                floatx4 acc;
                acc = __builtin_amdgcn_mfma_f32_16x16x32_bf16(f2[t][0], wf0, z4, 0, 0, 0);
                acc = __builtin_amdgcn_mfma_f32_16x16x32_bf16(f2[t][1], wf1, acc, 0, 0, 0);
                a3[t][mt] = acc;
            }
        }

        // ---- in-register pool over this wave's 32 x-rows ----
        float2 part[2];
#pragma unroll
        for (int mt = 0; mt < 2; ++mt) {
            floatx4 sv = a3[0][mt] + a3[1][mt];
            floatx4 mv = vmax4(a3[0][mt], a3[1][mt]);
            float s = (sv[0] + sv[1]) + (sv[2] + sv[3]);
            float m = fmaxf(fmaxf(mv[0], mv[1]), fmaxf(mv[2], mv[3]));
            s += __shfl_xor(s, 16); m = fmaxf(m, __shfl_xor(m, 16));
            s += __shfl_xor(s, 32); m = fmaxf(m, __shfl_xor(m, 32));
            part[mt] = make_float2(s, m);
        }

        if (it + 1 < ITERS) x_store<DIN>(sm.xs[cur ^ 1], tid, g);

        if (qd == 0) {
            sm.pb[pbuf * 128 + w * 32 + ln]      = part[0];
            sm.pb[pbuf * 128 + w * 32 + 16 + ln] = part[1];
        }
        __syncthreads();

        // ---- combine waves -> output (wave w holds rows [w*32,w*32+32)) ----
        if (tid < NB * 32) {
            const int b = tid >> 5, f = tid & 31;
            constexpr int WPB = 4 / NB;   // waves per batch
            float s = 0.0f, m = -3.4e38f;
#pragma unroll
            for (int wv = 0; wv < WPB; ++wv) {
                float2 v = sm.pb[pbuf * 128 + (b * WPB + wv) * 32 + f];
                s += v.x;
                m = fmaxf(m, v.y);
            }
            out[((size_t)bid * NB + b) * 32 + f] =
                (__bf16)(0.5f * (s * (1.0f / S) + m) + b3f);
        }
        cur ^= 1; pbuf ^= 1;
    }
}

__global__ __launch_bounds__(256, 8)
void enc_fused(const float* __restrict__ rX, const float* __restrict__ tX,
               const __bf16* __restrict__ wb,
               const float* __restrict__ rb2, const float* __restrict__ rb3,
               const float* __restrict__ tb2, const float* __restrict__ tb3,
               __bf16* __restrict__ remb, __bf16* __restrict__ temb)
{
    __shared__ EncSmem sm;
    if ((int)blockIdx.x < 2048)
        enc_loop<6, 64, 4>(sm, rX, wb, rb2, rb3, remb, blockIdx.x * 4);
    else
        enc_loop<7, 128, 8>(sm, tX, wb + 8192, tb2, tb3, temb,
                            ((int)blockIdx.x - 2048) * 8);
}

// ---------------------------------------------------------------------------
// Head, register-chained (R7 + vectorized staging): stage c (1 barrier), then
// L1->L2->L3->dot in regs per wave (16 rows each). hw2/hw3 k-permuted.
// ---------------------------------------------------------------------------
__global__ __launch_bounds__(256)
void head_mfma(const float* __restrict__ t0,
               const __bf16* __restrict__ remb, const __bf16* __restrict__ temb,
               const __bf16* __restrict__ hw1, const float* __restrict__ b1,
               const __bf16* __restrict__ hw2, const float* __restrict__ b2,
               const __bf16* __restrict__ hw3, const float* __restrict__ b3,
               const float* __restrict__ w4, const float* __restrict__ b4,
               float* __restrict__ out)
{
    __shared__ __align__(16) __bf16 cb[64 * 136];

    const int tid = threadIdx.x;
    const int w   = tid >> 6;
    const int l64 = tid & 63;
    const int ln  = l64 & 15;
    const int qd  = l64 >> 4;
    const int g0  = blockIdx.x * 64;

    // t0: 11 float4 per row, cvt+packed 8B stores
    for (int i = tid; i < 64 * 11; i += 256) {
        int r = i / 11, c = i - r * 11;
        float4 v = *(const float4*)&t0[(size_t)(g0 + r) * 44 + c * 4];
        union { __hip_bfloat162 h[2]; uint2 u; } t;
        t.h[0] = __float22bfloat162_rn({v.x, v.y});
        t.h[1] = __float22bfloat162_rn({v.z, v.w});
        *(uint2*)&cb[r * 136 + c * 4] = t.u;
    }
    // remb/temb: 4 x uint4 per row, one chunk per thread
    {
        int r = tid >> 2, q = tid & 3;
        uint4 a = *(const uint4*)&remb[(size_t)(g0 + r) * 32 + q * 8];
        uint4 b = *(const uint4*)&temb[(size_t)(g0 + r) * 32 + q * 8];
        __bf16* p = &cb[r * 136 + 44 + q * 8];
        *(uint2*)p       = make_uint2(a.x, a.y);
        *(uint2*)(p + 4) = make_uint2(a.z, a.w);
        __bf16* p2 = &cb[r * 136 + 76 + q * 8];
        *(uint2*)p2       = make_uint2(b.x, b.y);
        *(uint2*)(p2 + 4) = make_uint2(b.z, b.w);
    }
    // zero pad k in [108,128): 5 x uint2 per row
    for (int i = tid; i < 64 * 5; i += 256) {
        int r = i / 5, c = i - r * 5;
        *(uint2*)&cb[r * 136 + 108 + c * 4] = make_uint2(0u, 0u);
    }
    __syncthreads();

    bf16x8 cf[4];
#pragma unroll
    for (int kq = 0; kq < 4; ++kq)
        cf[kq] = ld_frag(&cb[(w * 16 + ln) * 136 + kq * 32 + qd * 8]);
    floatx4 acc1[8];
#pragma unroll
    for (int mt = 0; mt < 8; ++mt) {
        float4 bv = *(const float4*)&b1[mt * 16 + qd * 4];
        floatx4 acc = (floatx4){bv.x, bv.y, bv.z, bv.w};
#pragma unroll
        for (int kq = 0; kq < 4; ++kq) {
            bf16x8 af = ld_frag(&hw1[(mt * 16 + ln) * 128 + kq * 32 + qd * 8]);
            acc = __builtin_amdgcn_mfma_f32_16x16x32_bf16(af, cf[kq], acc, 0, 0, 0);
        }
        acc1[mt] = acc;
    }
    bf16x8 f1[4];
#pragma unroll
    for (int kq = 0; kq < 4; ++kq)
        f1[kq] = pack_relu2(acc1[2 * kq], acc1[2 * kq + 1]);

    floatx4 acc2[8];
#pragma unroll
    for (int mt = 0; mt < 8; ++mt) {
        float4 bv = *(const float4*)&b2[mt * 16 + qd * 4];
        floatx4 acc = (floatx4){bv.x, bv.y, bv.z, bv.w};
#pragma unroll
        for (int kq = 0; kq < 4; ++kq) {
            bf16x8 af = ld_frag(&hw2[(mt * 16 + ln) * 128 + kq * 32 + qd * 8]);
            acc = __builtin_amdgcn_mfma_f32_16x16x32_bf16(af, f1[kq], acc, 0, 0, 0);
        }
        acc2[mt] = acc;
    }
    bf16x8 f2[4];
#pragma unroll
    for (int kq = 0; kq < 4; ++kq)
        f2[kq] = pack_relu2(acc2[2 * kq], acc2[2 * kq + 1]);

    floatx4 acc3[4];
#pragma unroll
    for (int mt = 0; mt < 4; ++mt) {
        float4 bv = *(const float4*)&b3[mt * 16 + qd * 4];
        floatx4 acc = (floatx4){bv.x, bv.y, bv.z, bv.w};
#pragma unroll
        for (int kq = 0; kq < 4; ++kq) {
            bf16x8 af = ld_frag(&hw3[(mt * 16 + ln) * 128 + kq * 32 + qd * 8]);
            acc = __builtin_amdgcn_mfma_f32_16x16x32_bf16(af, f2[kq], acc, 0, 0, 0);
        }
        acc3[mt] = acc;
    }

    float part = 0.0f;
#pragma unroll
    for (int mt = 0; mt < 4; ++mt) {
        float4 wv = *(const float4*)&w4[mt * 16 + qd * 4];
        part = fmaf(fmaxf(acc3[mt][0], 0.0f), wv.x, part);
        part = fmaf(fmaxf(acc3[mt][1], 0.0f), wv.y, part);
        part = fmaf(fmaxf(acc3[mt][2], 0.0f), wv.z, part);
        part = fmaf(fmaxf(acc3[mt][3], 0.0f), wv.w, part);
    }
    part += __shfl_xor(part, 16);
    part += __shfl_xor(part, 32);
    if (qd == 0)
        out[g0 + w * 16 + ln] = part + b4[0];
}

extern "C" void kernel_launch(void* const* d_in, const int* in_sizes, int n_in,
                              void* d_out, int out_size, void* d_ws, size_t ws_size,
                              hipStream_t stream)
{
    const float* t0  = (const float*)d_in[0];
    const float* rX  = (const float*)d_in[1];
    const float* tX  = (const float*)d_in[2];
    const float* rw1 = (const float*)d_in[3];  const float* rb1 = (const float*)d_in[4];
    const float* rw2 = (const float*)d_in[5];  const float* rb2 = (const float*)d_in[6];
    const float* rw3 = (const float*)d_in[7];  const float* rb3 = (const float*)d_in[8];
    const float* tw1 = (const float*)d_in[9];  const float* tb1 = (const float*)d_in[10];
    const float* tw2 = (const float*)d_in[11]; const float* tb2 = (const float*)d_in[12];
    const float* tw3 = (const float*)d_in[13]; const float* tb3 = (const float*)d_in[14];
    const float* mw1 = (const float*)d_in[15]; const float* mb1 = (const float*)d_in[16];
    const float* mw2 = (const float*)d_in[17]; const float* mb2 = (const float*)d_in[18];
    const float* mw3 = (const float*)d_in[19]; const float* mb3 = (const float*)d_in[20];
    const float* mw4 = (const float*)d_in[21]; const float* mb4 = (const float*)d_in[22];
    float* out = (float*)d_out;

    const int B = 16384;
    __bf16* remb = (__bf16*)d_ws;
    __bf16* temb = (__bf16*)((char*)d_ws + ((size_t)1 << 20));
    __bf16* wb   = (__bf16*)((char*)d_ws + ((size_t)2 << 20));
    const __bf16* mw1b = wb + 16384; const __bf16* mw2b = wb + 32768;
    const __bf16* mw3b = wb + 49152;

    prep_kernel<<<64, 256, 0, stream>>>(rw1, rb1, rw2, rw3, tw1, tb1, tw2, tw3,
                                        mw1, mw2, mw3, wb);
    enc_fused<<<4096, 256, 0, stream>>>(rX, tX, wb,
                                        rb2, rb3, tb2, tb3,
                                        remb, temb);
    head_mfma<<<B / 64, 256, 0, stream>>>(t0, remb, temb,
                                          mw1b, mb1, mw2b, mb2, mw3b, mb3,
                                          mw4, mb4, out);
}

// Round 6
// 223.139 us; speedup vs baseline: 1.5419x; 1.5419x over previous
//
#include <hip/hip_runtime.h>
#include <hip/hip_bf16.h>

#define DEV_INLINE __device__ __forceinline__

typedef __bf16 bf16x8 __attribute__((ext_vector_type(8)));
typedef float  floatx4 __attribute__((ext_vector_type(4)));
typedef short  shortx2 __attribute__((ext_vector_type(2)));

DEV_INLINE bf16x8 ld_frag(const __bf16* p) {
    union { uint4 u; bf16x8 v; } t;
    t.u = *(const uint4*)p;
    return t.v;
}
// cvt-first relu+pack: convert two f32x4 accs to bf16, then clamp negatives
// via packed i16 max (sign-bit test == float x>0 test; exact vs fmax-then-cvt
// for all finite inputs). Element j = relu(acc[2kq + (j>>2)][j&3]).
DEV_INLINE bf16x8 pack_relu2(floatx4 a, floatx4 b) {
    union { __hip_bfloat162 h[4]; shortx2 s[4]; bf16x8 v; } t;
    t.h[0] = __float22bfloat162_rn({a[0], a[1]});
    t.h[1] = __float22bfloat162_rn({a[2], a[3]});
    t.h[2] = __float22bfloat162_rn({b[0], b[1]});
    t.h[3] = __float22bfloat162_rn({b[2], b[3]});
    const shortx2 z = {0, 0};
#pragma unroll
    for (int i = 0; i < 4; ++i) t.s[i] = __builtin_elementwise_max(t.s[i], z);
    return t.v;
}
DEV_INLINE floatx4 vmax4(floatx4 a, floatx4 b) {
    floatx4 r;
#pragma unroll
    for (int i = 0; i < 4; ++i) r[i] = fmaxf(a[i], b[i]);
    return r;
}

// ---------------------------------------------------------------------------
// Prep. tp: natural transpose+pad (A-layout [n][k]). tp_b: same, with the
// bias placed in padded row k==Ks (consumer sets x[k=Ks]=1.0). tp_perm:
// k-permuted so the consumer uses the previous layer's accumulators directly.
// ---------------------------------------------------------------------------
template<int N, int Kp, int Ks>
DEV_INLINE void tp(__bf16* dst, const float* __restrict__ src, int idx0, int stride) {
    for (int e = idx0; e < N * Kp; e += stride) {
        int n = e / Kp, k = e - n * Kp;
        dst[e] = (k < Ks) ? (__bf16)src[k * N + n] : (__bf16)0.0f;
    }
}
template<int N, int Kp, int Ks>
DEV_INLINE void tp_b(__bf16* dst, const float* __restrict__ src,
                     const float* __restrict__ bias, int idx0, int stride) {
    for (int e = idx0; e < N * Kp; e += stride) {
        int n = e / Kp, k = e - n * Kp;
        float v = (k < Ks) ? src[k * N + n] : ((k == Ks) ? bias[n] : 0.0f);
        dst[e] = (__bf16)v;
    }
}
template<int N, int K>   // dst[n][k_hw] = src[c(k_hw)][n]
DEV_INLINE void tp_perm(__bf16* dst, const float* __restrict__ src, int idx0, int stride) {
    for (int e = idx0; e < N * K; e += stride) {
        int n = e / K, kh = e - n * K;
        int qd = (kh >> 3) & 3, kq = kh >> 5, j = kh & 7;
        int c = (2 * kq + (j >> 2)) * 16 + qd * 4 + (j & 3);
        dst[e] = (__bf16)src[c * N + n];
    }
}

__global__ __launch_bounds__(256)
void prep_kernel(const float* __restrict__ rw1, const float* __restrict__ rb1,
                 const float* __restrict__ rw2, const float* __restrict__ rw3,
                 const float* __restrict__ tw1, const float* __restrict__ tb1,
                 const float* __restrict__ tw2, const float* __restrict__ tw3,
                 const float* __restrict__ mw1, const float* __restrict__ mw2,
                 const float* __restrict__ mw3, __bf16* __restrict__ wb)
{
    int i0 = blockIdx.x * 256 + threadIdx.x;
    int st = gridDim.x * 256;
    tp_b   < 64,  32,   6>(wb + 0,     rw1, rb1, i0, st);
    tp_perm< 64,  64>     (wb + 2048,  rw2, i0, st);
    tp_perm< 32,  64>     (wb + 6144,  rw3, i0, st);
    tp_b   < 64,  32,   7>(wb + 8192,  tw1, tb1, i0, st);
    tp_perm< 64,  64>     (wb + 10240, tw2, i0, st);
    tp_perm< 32,  64>     (wb + 14336, tw3, i0, st);
    tp     <128, 128, 108>(wb + 16384, mw1, i0, st);
    tp_perm<128, 128>     (wb + 32768, mw2, i0, st);
    tp_perm< 64, 128>     (wb + 49152, mw3, i0, st);
}

// ---------------------------------------------------------------------------
// Persistent fused encoder, R13 = R4's proven residency config (bound 6,
// grid 3072) + R5's conflict-free lane-major w2/w3 LDS + w1 in registers +
// packed-i16 relu + zero-stub unconditional x frag reads.
// R5 lesson: bound 8 (cap 64 regs) spills ~586 MB/dispatch -> never cap
// below ~85. Live state here ~52 regs.
// ---------------------------------------------------------------------------
struct __align__(16) EncSmem {
    __bf16 wt[6144];         // w2 lane-major (0..4095) | w3 (4096..6143) 12288 B
    __bf16 zx[8];            // 16B zero stub for qd!=0 frag reads
    float2 pb[2 * 128];      // wave partials (sum,max), dbuf  2048 B
    float  bs[64];           // b2                              256 B
    __bf16 xs[2][128 * 8];   // x tiles, k padded to 8         4096 B
};

template<int DIN>
DEV_INLINE void x_load(const float* __restrict__ X, int bid, int tid, float (&g)[4]) {
    const float* src = X + (size_t)bid * 128 * DIN;
#pragma unroll
    for (int p = 0; p < 4; ++p) {
        int e = tid + p * 256;
        if ((DIN == 6) ? (p < 3) : (e < 128 * 7)) g[p] = src[e];
    }
}
template<int DIN>
DEV_INLINE void x_store(__bf16* xbuf, int tid, const float (&g)[4]) {
#pragma unroll
    for (int p = 0; p < 4; ++p) {
        int e = tid + p * 256;
        if ((DIN == 6) ? (p < 3) : (e < 128 * 7)) {
            int r = e / DIN, k = e - r * DIN;
            xbuf[r * 8 + k] = (__bf16)g[p];
        }
    }
}

template<int DIN, int S, int ITERS>
DEV_INLINE void enc_loop(EncSmem& sm, const float* __restrict__ X,
                         const __bf16* __restrict__ wsrc,
                         const float* __restrict__ b2, const float* __restrict__ b3,
                         __bf16* __restrict__ out, int bid0)
{
    constexpr int NB = 128 / S;          // batches per 128-row tile
    const int tid = threadIdx.x;
    const int w   = tid >> 6;
    const int l64 = tid & 63;
    const int ln  = l64 & 15;
    const int qd  = l64 >> 4;

    if (tid < 64) sm.bs[tid] = b2[tid];
    if (tid == 0) *(uint4*)sm.zx = make_uint4(0u, 0u, 0u, 0u);

    // ---- w2/w3 -> LDS, lane-major frag order (768 x 16B chunks) ----
    // src chunk cs of tensor: n = cs>>3 (row), r = cs&7; frag owner lane
    // l64 = (r&3)*16 + (n&15); dst chunk = ((n>>4)*2 + (r>>2))*64 + l64.
    for (int c = tid; c < 768; c += 256) {
        const bool isw2 = c < 512;
        const int cs = isw2 ? c : c - 512;
        uint4 v = *(const uint4*)(wsrc + (isw2 ? 2048 : 6144) + cs * 8);
        int n = cs >> 3, r = cs & 7;
        int cd = ((n >> 4) * 2 + (r >> 2)) * 64 + (r & 3) * 16 + (n & 15);
        *(uint4*)&sm.wt[(isw2 ? 0 : 4096) + cd * 8] = v;
    }

    // pad init: k in [DIN,8) of both x buffers; bias slot k==DIN gets 1.0
    {
        __bf16* xf = &sm.xs[0][0];
        if (DIN == 6) {
            union { __bf16 h[2]; uint32_t u; } c;
            c.h[0] = (__bf16)1.0f; c.h[1] = (__bf16)0.0f;
            *(uint32_t*)&xf[tid * 8 + 6] = c.u;   // rows 0..255 across both bufs
        } else {
            xf[tid * 8 + 7] = (__bf16)1.0f;
        }
    }
    // b3 folded past pooling: e-row = Wx + b3 -> 0.5*(mean+max) = 0.5*(s/S+m)+b3[f]
    const float b3f = (tid < NB * 32) ? b3[tid & 31] : 0.0f;

    // ---- w1 frags -> registers, once per block (global, L2-resident) ----
    bf16x8 w1f[4];
#pragma unroll
    for (int mt = 0; mt < 4; ++mt)
        w1f[mt] = ld_frag(&wsrc[(mt * 16 + ln) * 32 + qd * 8]);

    const __bf16* wl = &sm.wt[l64 * 8];   // lane-major base (byte l64*16)
    const floatx4 z4 = {0.0f, 0.0f, 0.0f, 0.0f};

    // ---- prologue: stage x for iter 0 ----
    float g[4];
    x_load<DIN>(X, bid0, tid, g);
    x_store<DIN>(sm.xs[0], tid, g);
    __syncthreads();

    int cur = 0, pbuf = 0;
    for (int it = 0; it < ITERS; ++it) {
        const int bid = bid0 + it;
        // issue next tile's global loads early; stored late (latency hidden
        // under the whole L1->L3 compute). Writing xs[cur^1] needs no barrier:
        // its last reads were ordered by the previous iter's barrier.
        if (it + 1 < ITERS) x_load<DIN>(X, bid + 1, tid, g);

        // ---- x B-frags: unconditional ds_read; qd!=0 lanes hit the 16B
        // zero stub (same-address broadcast, conflict-free) ----
        bf16x8 xb[2];
#pragma unroll
        for (int t = 0; t < 2; ++t) {
            const int row = (2 * w + t) * 16 + ln;
            const __bf16* p = (qd == 0) ? &sm.xs[cur][row * 8] : sm.zx;
            xb[t] = ld_frag(p);
        }

        // ---- L1: K=32 (b1 in weight pad row, x pad=1.0), C = 0 ----
        floatx4 a1[2][4];
#pragma unroll
        for (int mt = 0; mt < 4; ++mt)
#pragma unroll
            for (int t = 0; t < 2; ++t)
                a1[t][mt] = __builtin_amdgcn_mfma_f32_16x16x32_bf16(w1f[mt], xb[t], z4, 0, 0, 0);
        bf16x8 f1[2][2];
#pragma unroll
        for (int t = 0; t < 2; ++t)
#pragma unroll
            for (int kq = 0; kq < 2; ++kq)
                f1[t][kq] = pack_relu2(a1[t][2 * kq], a1[t][2 * kq + 1]);

        // ---- L2: 64 -> 64, rolling a2 -> f2 per mt-pair (reg cap) ----
        bf16x8 f2[2][2];
#pragma unroll
        for (int pr = 0; pr < 2; ++pr) {
            floatx4 a2[2][2];
#pragma unroll
            for (int m = 0; m < 2; ++m) {
                const int mt = pr * 2 + m;
                floatx4 bv = *(const floatx4*)&sm.bs[mt * 16 + qd * 4];
                bf16x8 wf0 = ld_frag(&wl[(mt * 2 + 0) * 512]);
                bf16x8 wf1 = ld_frag(&wl[(mt * 2 + 1) * 512]);
#pragma unroll
                for (int t = 0; t < 2; ++t) {
                    floatx4 acc;
                    acc = __builtin_amdgcn_mfma_f32_16x16x32_bf16(wf0, f1[t][0], bv, 0, 0, 0);
                    acc = __builtin_amdgcn_mfma_f32_16x16x32_bf16(wf1, f1[t][1], acc, 0, 0, 0);
                    a2[t][m] = acc;
                }
            }
#pragma unroll
            for (int t = 0; t < 2; ++t)
                f2[t][pr] = pack_relu2(a2[t][0], a2[t][1]);
        }

        // ---- L3 FLIPPED: A=f2 (rows=x-rows), B=w3 (cols=features), C=0.
        // a3[t][mt][jj] = e[xrow=(2w+t)*16+qd*4+jj][feat=mt*16+ln]
        floatx4 a3[2][2];
#pragma unroll
        for (int mt = 0; mt < 2; ++mt) {
            bf16x8 wf0 = ld_frag(&wl[4096 + (mt * 2 + 0) * 512]);
            bf16x8 wf1 = ld_frag(&wl[4096 + (mt * 2 + 1) * 512]);
#pragma unroll
            for (int t = 0; t < 2; ++t) {
                floatx4 acc;
                acc = __builtin_amdgcn_mfma_f32_16x16x32_bf16(f2[t][0], wf0, z4, 0, 0, 0);
                acc = __builtin_amdgcn_mfma_f32_16x16x32_bf16(f2[t][1], wf1, acc, 0, 0, 0);
                a3[t][mt] = acc;
            }
        }

        // ---- in-register pool over this wave's 32 x-rows ----
        float2 part[2];
#pragma unroll
        for (int mt = 0; mt < 2; ++mt) {
            floatx4 sv = a3[0][mt] + a3[1][mt];
            floatx4 mv = vmax4(a3[0][mt], a3[1][mt]);
            float s = (sv[0] + sv[1]) + (sv[2] + sv[3]);
            float m = fmaxf(fmaxf(mv[0], mv[1]), fmaxf(mv[2], mv[3]));
            s += __shfl_xor(s, 16); m = fmaxf(m, __shfl_xor(m, 16));
            s += __shfl_xor(s, 32); m = fmaxf(m, __shfl_xor(m, 32));
            part[mt] = make_float2(s, m);
        }

        if (it + 1 < ITERS) x_store<DIN>(sm.xs[cur ^ 1], tid, g);

        if (qd == 0) {
            sm.pb[pbuf * 128 + w * 32 + ln]      = part[0];
            sm.pb[pbuf * 128 + w * 32 + 16 + ln] = part[1];
        }
        __syncthreads();

        // ---- combine waves -> output (wave w holds rows [w*32,w*32+32)) ----
        if (tid < NB * 32) {
            const int b = tid >> 5, f = tid & 31;
            constexpr int WPB = 4 / NB;   // waves per batch
            float s = 0.0f, m = -3.4e38f;
#pragma unroll
            for (int wv = 0; wv < WPB; ++wv) {
                float2 v = sm.pb[pbuf * 128 + (b * WPB + wv) * 32 + f];
                s += v.x;
                m = fmaxf(m, v.y);
            }
            out[((size_t)bid * NB + b) * 32 + f] =
                (__bf16)(0.5f * (s * (1.0f / S) + m) + b3f);
        }
        cur ^= 1; pbuf ^= 1;
    }
}

__global__ __launch_bounds__(256, 6)
void enc_fused(const float* __restrict__ rX, const float* __restrict__ tX,
               const __bf16* __restrict__ wb,
               const float* __restrict__ rb2, const float* __restrict__ rb3,
               const float* __restrict__ tb2, const float* __restrict__ tb3,
               __bf16* __restrict__ remb, __bf16* __restrict__ temb)
{
    __shared__ EncSmem sm;
    if ((int)blockIdx.x < 1024)
        enc_loop<6, 64, 8>(sm, rX, wb, rb2, rb3, remb, blockIdx.x * 8);
    else
        enc_loop<7, 128, 8>(sm, tX, wb + 8192, tb2, tb3, temb,
                            ((int)blockIdx.x - 1024) * 8);
}

// ---------------------------------------------------------------------------
// Head, register-chained (R7 + vectorized staging): stage c (1 barrier), then
// L1->L2->L3->dot in regs per wave (16 rows each). hw2/hw3 k-permuted.
// ---------------------------------------------------------------------------
__global__ __launch_bounds__(256)
void head_mfma(const float* __restrict__ t0,
               const __bf16* __restrict__ remb, const __bf16* __restrict__ temb,
               const __bf16* __restrict__ hw1, const float* __restrict__ b1,
               const __bf16* __restrict__ hw2, const float* __restrict__ b2,
               const __bf16* __restrict__ hw3, const float* __restrict__ b3,
               const float* __restrict__ w4, const float* __restrict__ b4,
               float* __restrict__ out)
{
    __shared__ __align__(16) __bf16 cb[64 * 136];

    const int tid = threadIdx.x;
    const int w   = tid >> 6;
    const int l64 = tid & 63;
    const int ln  = l64 & 15;
    const int qd  = l64 >> 4;
    const int g0  = blockIdx.x * 64;

    // t0: 11 float4 per row, cvt+packed 8B stores
    for (int i = tid; i < 64 * 11; i += 256) {
        int r = i / 11, c = i - r * 11;
        float4 v = *(const float4*)&t0[(size_t)(g0 + r) * 44 + c * 4];
        union { __hip_bfloat162 h[2]; uint2 u; } t;
        t.h[0] = __float22bfloat162_rn({v.x, v.y});
        t.h[1] = __float22bfloat162_rn({v.z, v.w});
        *(uint2*)&cb[r * 136 + c * 4] = t.u;
    }
    // remb/temb: 4 x uint4 per row, one chunk per thread
    {
        int r = tid >> 2, q = tid & 3;
        uint4 a = *(const uint4*)&remb[(size_t)(g0 + r) * 32 + q * 8];
        uint4 b = *(const uint4*)&temb[(size_t)(g0 + r) * 32 + q * 8];
        __bf16* p = &cb[r * 136 + 44 + q * 8];
        *(uint2*)p       = make_uint2(a.x, a.y);
        *(uint2*)(p + 4) = make_uint2(a.z, a.w);
        __bf16* p2 = &cb[r * 136 + 76 + q * 8];
        *(uint2*)p2       = make_uint2(b.x, b.y);
        *(uint2*)(p2 + 4) = make_uint2(b.z, b.w);
    }
    // zero pad k in [108,128): 5 x uint2 per row
    for (int i = tid; i < 64 * 5; i += 256) {
        int r = i / 5, c = i - r * 5;
        *(uint2*)&cb[r * 136 + 108 + c * 4] = make_uint2(0u, 0u);
    }
    __syncthreads();

    bf16x8 cf[4];
#pragma unroll
    for (int kq = 0; kq < 4; ++kq)
        cf[kq] = ld_frag(&cb[(w * 16 + ln) * 136 + kq * 32 + qd * 8]);
    floatx4 acc1[8];
#pragma unroll
    for (int mt = 0; mt < 8; ++mt) {
        float4 bv = *(const float4*)&b1[mt * 16 + qd * 4];
        floatx4 acc = (floatx4){bv.x, bv.y, bv.z, bv.w};
#pragma unroll
        for (int kq = 0; kq < 4; ++kq) {
            bf16x8 af = ld_frag(&hw1[(mt * 16 + ln) * 128 + kq * 32 + qd * 8]);
            acc = __builtin_amdgcn_mfma_f32_16x16x32_bf16(af, cf[kq], acc, 0, 0, 0);
        }
        acc1[mt] = acc;
    }
    bf16x8 f1[4];
#pragma unroll
    for (int kq = 0; kq < 4; ++kq)
        f1[kq] = pack_relu2(acc1[2 * kq], acc1[2 * kq + 1]);

    floatx4 acc2[8];
#pragma unroll
    for (int mt = 0; mt < 8; ++mt) {
        float4 bv = *(const float4*)&b2[mt * 16 + qd * 4];
        floatx4 acc = (floatx4){bv.x, bv.y, bv.z, bv.w};
#pragma unroll
        for (int kq = 0; kq < 4; ++kq) {
            bf16x8 af = ld_frag(&hw2[(mt * 16 + ln) * 128 + kq * 32 + qd * 8]);
            acc = __builtin_amdgcn_mfma_f32_16x16x32_bf16(af, f1[kq], acc, 0, 0, 0);
        }
        acc2[mt] = acc;
    }
    bf16x8 f2[4];
#pragma unroll
    for (int kq = 0; kq < 4; ++kq)
        f2[kq] = pack_relu2(acc2[2 * kq], acc2[2 * kq + 1]);

    floatx4 acc3[4];
#pragma unroll
    for (int mt = 0; mt < 4; ++mt) {
        float4 bv = *(const float4*)&b3[mt * 16 + qd * 4];
        floatx4 acc = (floatx4){bv.x, bv.y, bv.z, bv.w};
#pragma unroll
        for (int kq = 0; kq < 4; ++kq) {
            bf16x8 af = ld_frag(&hw3[(mt * 16 + ln) * 128 + kq * 32 + qd * 8]);
            acc = __builtin_amdgcn_mfma_f32_16x16x32_bf16(af, f2[kq], acc, 0, 0, 0);
        }
        acc3[mt] = acc;
    }

    float part = 0.0f;
#pragma unroll
    for (int mt = 0; mt < 4; ++mt) {
        float4 wv = *(const float4*)&w4[mt * 16 + qd * 4];
        part = fmaf(fmaxf(acc3[mt][0], 0.0f), wv.x, part);
        part = fmaf(fmaxf(acc3[mt][1], 0.0f), wv.y, part);
        part = fmaf(fmaxf(acc3[mt][2], 0.0f), wv.z, part);
        part = fmaf(fmaxf(acc3[mt][3], 0.0f), wv.w, part);
    }
    part += __shfl_xor(part, 16);
    part += __shfl_xor(part, 32);
    if (qd == 0)
        out[g0 + w * 16 + ln] = part + b4[0];
}

extern "C" void kernel_launch(void* const* d_in, const int* in_sizes, int n_in,
                              void* d_out, int out_size, void* d_ws, size_t ws_size,
                              hipStream_t stream)
{
    const float* t0  = (const float*)d_in[0];
    const float* rX  = (const float*)d_in[1];
    const float* tX  = (const float*)d_in[2];
    const float* rw1 = (const float*)d_in[3];  const float* rb1 = (const float*)d_in[4];
    const float* rw2 = (const float*)d_in[5];  const float* rb2 = (const float*)d_in[6];
    const float* rw3 = (const float*)d_in[7];  const float* rb3 = (const float*)d_in[8];
    const float* tw1 = (const float*)d_in[9];  const float* tb1 = (const float*)d_in[10];
    const float* tw2 = (const float*)d_in[11]; const float* tb2 = (const float*)d_in[12];
    const float* tw3 = (const float*)d_in[13]; const float* tb3 = (const float*)d_in[14];
    const float* mw1 = (const float*)d_in[15]; const float* mb1 = (const float*)d_in[16];
    const float* mw2 = (const float*)d_in[17]; const float* mb2 = (const float*)d_in[18];
    const float* mw3 = (const float*)d_in[19]; const float* mb3 = (const float*)d_in[20];
    const float* mw4 = (const float*)d_in[21]; const float* mb4 = (const float*)d_in[22];
    float* out = (float*)d_out;

    const int B = 16384;
    __bf16* remb = (__bf16*)d_ws;
    __bf16* temb = (__bf16*)((char*)d_ws + ((size_t)1 << 20));
    __bf16* wb   = (__bf16*)((char*)d_ws + ((size_t)2 << 20));
    const __bf16* mw1b = wb + 16384; const __bf16* mw2b = wb + 32768;
    const __bf16* mw3b = wb + 49152;

    prep_kernel<<<64, 256, 0, stream>>>(rw1, rb1, rw2, rw3, tw1, tb1, tw2, tw3,
                                        mw1, mw2, mw3, wb);
    enc_fused<<<3072, 256, 0, stream>>>(rX, tX, wb,
                                        rb2, rb3, tb2, tb3,
                                        remb, temb);
    head_mfma<<<B / 64, 256, 0, stream>>>(t0, remb, temb,
                                          mw1b, mb1, mw2b, mb2, mw3b, mb3,
                                          mw4, mb4, out);
}

// Round 8
// 206.039 us; speedup vs baseline: 1.6699x; 1.0830x over previous
//
#include <hip/hip_runtime.h>
#include <hip/hip_bf16.h>

#define DEV_INLINE __device__ __forceinline__

typedef __bf16 bf16x8 __attribute__((ext_vector_type(8)));
typedef __bf16 bf16x4 __attribute__((ext_vector_type(4)));
typedef float  floatx4 __attribute__((ext_vector_type(4)));
typedef short  shortx8 __attribute__((ext_vector_type(8)));

DEV_INLINE bf16x8 ld_frag(const __bf16* p) {
    union { uint4 u; bf16x8 v; } t;
    t.u = *(const uint4*)p;
    return t.v;
}
// cvt-first relu+pack, union-free (R6/R7 lessons: mixed-type unions defeat
// SROA -> scratch; __hip_bfloat162 is not trivially copyable -> no bit_cast).
// Scalar (__bf16) casts fuse into v_cvt_pk_bf16_f32; then packed i16 max
// clamps negatives (sign-bit test == float relu for all finite values).
// Element j = relu(acc[2kq + (j>>2)][j&3]).
DEV_INLINE bf16x8 pack_relu2(floatx4 a, floatx4 b) {
    bf16x8 r = {(__bf16)a[0], (__bf16)a[1], (__bf16)a[2], (__bf16)a[3],
                (__bf16)b[0], (__bf16)b[1], (__bf16)b[2], (__bf16)b[3]};
    shortx8 s = __builtin_bit_cast(shortx8, r);
    const shortx8 z = {0, 0, 0, 0, 0, 0, 0, 0};
    s = __builtin_elementwise_max(s, z);
    return __builtin_bit_cast(bf16x8, s);
}
DEV_INLINE floatx4 vmax4(floatx4 a, floatx4 b) {
    floatx4 r;
#pragma unroll
    for (int i = 0; i < 4; ++i) r[i] = fmaxf(a[i], b[i]);
    return r;
}

// ---------------------------------------------------------------------------
// Prep. tp: natural transpose+pad (A-layout [n][k]). tp_b: same, with the
// bias placed in padded row k==Ks (consumer sets x[k=Ks]=1.0). tp_perm:
// k-permuted so the consumer uses the previous layer's accumulators directly.
// ---------------------------------------------------------------------------
template<int N, int Kp, int Ks>
DEV_INLINE void tp(__bf16* dst, const float* __restrict__ src, int idx0, int stride) {
    for (int e = idx0; e < N * Kp; e += stride) {
        int n = e / Kp, k = e - n * Kp;
        dst[e] = (k < Ks) ? (__bf16)src[k * N + n] : (__bf16)0.0f;
    }
}
template<int N, int Kp, int Ks>
DEV_INLINE void tp_b(__bf16* dst, const float* __restrict__ src,
                     const float* __restrict__ bias, int idx0, int stride) {
    for (int e = idx0; e < N * Kp; e += stride) {
        int n = e / Kp, k = e - n * Kp;
        float v = (k < Ks) ? src[k * N + n] : ((k == Ks) ? bias[n] : 0.0f);
        dst[e] = (__bf16)v;
    }
}
template<int N, int K>   // dst[n][k_hw] = src[c(k_hw)][n]
DEV_INLINE void tp_perm(__bf16* dst, const float* __restrict__ src, int idx0, int stride) {
    for (int e = idx0; e < N * K; e += stride) {
        int n = e / K, kh = e - n * K;
        int qd = (kh >> 3) & 3, kq = kh >> 5, j = kh & 7;
        int c = (2 * kq + (j >> 2)) * 16 + qd * 4 + (j & 3);
        dst[e] = (__bf16)src[c * N + n];
    }
}

__global__ __launch_bounds__(256)
void prep_kernel(const float* __restrict__ rw1, const float* __restrict__ rb1,
                 const float* __restrict__ rw2, const float* __restrict__ rw3,
                 const float* __restrict__ tw1, const float* __restrict__ tb1,
                 const float* __restrict__ tw2, const float* __restrict__ tw3,
                 const float* __restrict__ mw1, const float* __restrict__ mw2,
                 const float* __restrict__ mw3, __bf16* __restrict__ wb)
{
    int i0 = blockIdx.x * 256 + threadIdx.x;
    int st = gridDim.x * 256;
    tp_b   < 64,  32,   6>(wb + 0,     rw1, rb1, i0, st);
    tp_perm< 64,  64>     (wb + 2048,  rw2, i0, st);
    tp_perm< 32,  64>     (wb + 6144,  rw3, i0, st);
    tp_b   < 64,  32,   7>(wb + 8192,  tw1, tb1, i0, st);
    tp_perm< 64,  64>     (wb + 10240, tw2, i0, st);
    tp_perm< 32,  64>     (wb + 14336, tw3, i0, st);
    tp     <128, 128, 108>(wb + 16384, mw1, i0, st);
    tp_perm<128, 128>     (wb + 32768, mw2, i0, st);
    tp_perm< 64, 128>     (wb + 49152, mw3, i0, st);
}

// ---------------------------------------------------------------------------
// Persistent fused encoder, R15 = R4/R11 (proven 70.5us: all weights in LDS
// with XOR swizzle, bound 6, grid 3072) + union-free cvt-first packed-i16
// relu + zero-stub unconditional x frag reads. R4's empirically-best weight
// layout kept (lane-major had MORE conflicts, R6). R5 lesson: never cap regs
// below ~85 (bound 6 => cap ~85).
// ---------------------------------------------------------------------------
struct __align__(16) EncSmem {
    __bf16 wt[8192];         // w1(0..4095B) | w2(4096..) | w3(12288..)  16 KB
    __bf16 zx[8];            // 16B zero stub for qd!=0 frag reads
    float2 pb[2 * 128];      // wave partials (sum,max), dbuf  2048 B
    float  bs[64];           // b2                              256 B
    __bf16 xs[2][128 * 8];   // x tiles, k padded to 8         4096 B
};

template<int DIN>
DEV_INLINE void x_load(const float* __restrict__ X, int bid, int tid, float (&g)[4]) {
    const float* src = X + (size_t)bid * 128 * DIN;
#pragma unroll
    for (int p = 0; p < 4; ++p) {
        int e = tid + p * 256;
        if ((DIN == 6) ? (p < 3) : (e < 128 * 7)) g[p] = src[e];
    }
}
template<int DIN>
DEV_INLINE void x_store(__bf16* xbuf, int tid, const float (&g)[4]) {
#pragma unroll
    for (int p = 0; p < 4; ++p) {
        int e = tid + p * 256;
        if ((DIN == 6) ? (p < 3) : (e < 128 * 7)) {
            int r = e / DIN, k = e - r * DIN;
            xbuf[r * 8 + k] = (__bf16)g[p];
        }
    }
}

template<int DIN, int S, int ITERS>
DEV_INLINE void enc_loop(EncSmem& sm, const float* __restrict__ X,
                         const __bf16* __restrict__ wsrc,
                         const float* __restrict__ b2, const float* __restrict__ b3,
                         __bf16* __restrict__ out, int bid0)
{
    constexpr int NB = 128 / S;          // batches per 128-row tile
    const int tid = threadIdx.x;
    const int w   = tid >> 6;
    const int l64 = tid & 63;
    const int ln  = l64 & 15;
    const int qd  = l64 >> 4;

    if (tid < 64) sm.bs[tid] = b2[tid];
    if (tid == 0) *(uint4*)sm.zx = make_uint4(0u, 0u, 0u, 0u);

    // ---- weights -> LDS once per block (swizzled copy, 4 chunks/thread) ----
    for (int c = tid; c < 1024; c += 256) {
        uint4 v = *(const uint4*)(wsrc + c * 8);
        int byte = c * 16;
        int dst  = (c < 256) ? byte                                   // w1: no swizzle
                             : (byte ^ (((byte >> 7) & 7) << 4));     // w2/w3: row&7 xor
        *(uint4*)((char*)sm.wt + dst) = v;
    }

    // pad init: k in [DIN,8) of both x buffers; bias slot k==DIN gets 1.0
    {
        __bf16* xf = &sm.xs[0][0];
        if (DIN == 6) {
            __bf16 c0 = (__bf16)1.0f, c1 = (__bf16)0.0f;
            xf[tid * 8 + 6] = c0;
            xf[tid * 8 + 7] = c1;   // rows 0..255 across both bufs
        } else {
            xf[tid * 8 + 7] = (__bf16)1.0f;
        }
    }
    // b3 folded past pooling: e-row = Wx + b3 -> 0.5*(mean+max) = 0.5*(s/S+m)+b3[f]
    const float b3f = (tid < NB * 32) ? b3[tid & 31] : 0.0f;

    // per-thread weight base byte offsets (swizzle folded in; mt/kq offsets
    // are compile-time immediates that don't touch the swizzled bits)
    const int wb1   = (ln * 32 + qd * 8) * 2;                               // w1, stride 64B
    const int wb64a = ((ln * 64 + qd * 8) * 2)       ^ ((ln & 7) << 4);     // w2/w3 kq=0
    const int wb64b = ((ln * 64 + 32 + qd * 8) * 2)  ^ ((ln & 7) << 4);     // w2/w3 kq=1
    const char* wtb = (const char*)sm.wt;

    const floatx4 z4 = {0.0f, 0.0f, 0.0f, 0.0f};

    // ---- prologue: stage x for iter 0 ----
    float g[4];
    x_load<DIN>(X, bid0, tid, g);
    x_store<DIN>(sm.xs[0], tid, g);
    __syncthreads();

    int cur = 0, pbuf = 0;
    for (int it = 0; it < ITERS; ++it) {
        const int bid = bid0 + it;
        // issue next tile's global loads early; stored late (latency hidden
        // under the whole L1->L3 compute). Writing xs[cur^1] needs no barrier:
        // its last reads were ordered by the previous iter's barrier.
        if (it + 1 < ITERS) x_load<DIN>(X, bid + 1, tid, g);

        // ---- x B-frags: unconditional ds_read; qd!=0 lanes hit the 16B
        // zero stub (same-address broadcast, conflict-free) ----
        bf16x8 xb[2];
#pragma unroll
        for (int t = 0; t < 2; ++t) {
            const int row = (2 * w + t) * 16 + ln;
            const __bf16* p = (qd == 0) ? &sm.xs[cur][row * 8] : sm.zx;
            xb[t] = ld_frag(p);
        }

        // ---- L1: K=32 (b1 in weight pad row, x pad=1.0), C = 0 ----
        floatx4 a1[2][4];
#pragma unroll
        for (int mt = 0; mt < 4; ++mt) {
            bf16x8 wf = ld_frag((const __bf16*)(wtb + wb1 + mt * 1024));
#pragma unroll
            for (int t = 0; t < 2; ++t)
                a1[t][mt] = __builtin_amdgcn_mfma_f32_16x16x32_bf16(wf, xb[t], z4, 0, 0, 0);
        }
        bf16x8 f1[2][2];
#pragma unroll
        for (int t = 0; t < 2; ++t)
#pragma unroll
            for (int kq = 0; kq < 2; ++kq)
                f1[t][kq] = pack_relu2(a1[t][2 * kq], a1[t][2 * kq + 1]);

        // ---- L2: 64 -> 64, rolling a2 -> f2 per mt-pair (reg cap) ----
        bf16x8 f2[2][2];
#pragma unroll
        for (int pr = 0; pr < 2; ++pr) {
            floatx4 a2[2][2];
#pragma unroll
            for (int m = 0; m < 2; ++m) {
                const int mt = pr * 2 + m;
                floatx4 bv = *(const floatx4*)&sm.bs[mt * 16 + qd * 4];
                bf16x8 wf0 = ld_frag((const __bf16*)(wtb + 4096 + mt * 2048 + wb64a));
                bf16x8 wf1 = ld_frag((const __bf16*)(wtb + 4096 + mt * 2048 + wb64b));
#pragma unroll
                for (int t = 0; t < 2; ++t) {
                    floatx4 acc;
                    acc = __builtin_amdgcn_mfma_f32_16x16x32_bf16(wf0, f1[t][0], bv, 0, 0, 0);
                    acc = __builtin_amdgcn_mfma_f32_16x16x32_bf16(wf1, f1[t][1], acc, 0, 0, 0);
                    a2[t][m] = acc;
                }
            }
#pragma unroll
            for (int t = 0; t < 2; ++t)
                f2[t][pr] = pack_relu2(a2[t][0], a2[t][1]);
        }

        // ---- L3 FLIPPED: A=f2 (rows=x-rows), B=w3 (cols=features), C=0.
        // a3[t][mt][jj] = e[xrow=(2w+t)*16+qd*4+jj][feat=mt*16+ln]
        floatx4 a3[2][2];
#pragma unroll
        for (int mt = 0; mt < 2; ++mt) {
            bf16x8 wf0 = ld_frag((const __bf16*)(wtb + 12288 + mt * 2048 + wb64a));
            bf16x8 wf1 = ld_frag((const __bf16*)(wtb + 12288 + mt * 2048 + wb64b));
#pragma unroll
            for (int t = 0; t < 2; ++t) {
                floatx4 acc;
                acc = __builtin_amdgcn_mfma_f32_16x16x32_bf16(f2[t][0], wf0, z4, 0, 0, 0);
                acc = __builtin_amdgcn_mfma_f32_16x16x32_bf16(f2[t][1], wf1, acc, 0, 0, 0);
                a3[t][mt] = acc;
            }
        }

        // ---- in-register pool over this wave's 32 x-rows ----
        float2 part[2];
#pragma unroll
        for (int mt = 0; mt < 2; ++mt) {
            floatx4 sv = a3[0][mt] + a3[1][mt];
            floatx4 mv = vmax4(a3[0][mt], a3[1][mt]);
            float s = (sv[0] + sv[1]) + (sv[2] + sv[3]);
            float m = fmaxf(fmaxf(mv[0], mv[1]), fmaxf(mv[2], mv[3]));
            s += __shfl_xor(s, 16); m = fmaxf(m, __shfl_xor(m, 16));
            s += __shfl_xor(s, 32); m = fmaxf(m, __shfl_xor(m, 32));
            part[mt] = make_float2(s, m);
        }

        if (it + 1 < ITERS) x_store<DIN>(sm.xs[cur ^ 1], tid, g);

        if (qd == 0) {
            sm.pb[pbuf * 128 + w * 32 + ln]      = part[0];
            sm.pb[pbuf * 128 + w * 32 + 16 + ln] = part[1];
        }
        __syncthreads();

        // ---- combine waves -> output (wave w holds rows [w*32,w*32+32)) ----
        if (tid < NB * 32) {
            const int b = tid >> 5, f = tid & 31;
            constexpr int WPB = 4 / NB;   // waves per batch
            float s = 0.0f, m = -3.4e38f;
#pragma unroll
            for (int wv = 0; wv < WPB; ++wv) {
                float2 v = sm.pb[pbuf * 128 + (b * WPB + wv) * 32 + f];
                s += v.x;
                m = fmaxf(m, v.y);
            }
            out[((size_t)bid * NB + b) * 32 + f] =
                (__bf16)(0.5f * (s * (1.0f / S) + m) + b3f);
        }
        cur ^= 1; pbuf ^= 1;
    }
}

__global__ __launch_bounds__(256, 6)
void enc_fused(const float* __restrict__ rX, const float* __restrict__ tX,
               const __bf16* __restrict__ wb,
               const float* __restrict__ rb2, const float* __restrict__ rb3,
               const float* __restrict__ tb2, const float* __restrict__ tb3,
               __bf16* __restrict__ remb, __bf16* __restrict__ temb)
{
    __shared__ EncSmem sm;
    if ((int)blockIdx.x < 1024)
        enc_loop<6, 64, 8>(sm, rX, wb, rb2, rb3, remb, blockIdx.x * 8);
    else
        enc_loop<7, 128, 8>(sm, tX, wb + 8192, tb2, tb3, temb,
                            ((int)blockIdx.x - 1024) * 8);
}

// ---------------------------------------------------------------------------
// Head, register-chained (R7 + vectorized staging): stage c (1 barrier), then
// L1->L2->L3->dot in regs per wave (16 rows each). hw2/hw3 k-permuted.
// ---------------------------------------------------------------------------
__global__ __launch_bounds__(256)
void head_mfma(const float* __restrict__ t0,
               const __bf16* __restrict__ remb, const __bf16* __restrict__ temb,
               const __bf16* __restrict__ hw1, const float* __restrict__ b1,
               const __bf16* __restrict__ hw2, const float* __restrict__ b2,
               const __bf16* __restrict__ hw3, const float* __restrict__ b3,
               const float* __restrict__ w4, const float* __restrict__ b4,
               float* __restrict__ out)
{
    __shared__ __align__(16) __bf16 cb[64 * 136];

    const int tid = threadIdx.x;
    const int w   = tid >> 6;
    const int l64 = tid & 63;
    const int ln  = l64 & 15;
    const int qd  = l64 >> 4;
    const int g0  = blockIdx.x * 64;

    // t0: 11 float4 per row, cvt + 8B bf16x4 stores
    for (int i = tid; i < 64 * 11; i += 256) {
        int r = i / 11, c = i - r * 11;
        float4 v = *(const float4*)&t0[(size_t)(g0 + r) * 44 + c * 4];
        bf16x4 t = {(__bf16)v.x, (__bf16)v.y, (__bf16)v.z, (__bf16)v.w};
        *(bf16x4*)&cb[r * 136 + c * 4] = t;
    }
    // remb/temb: 4 x uint4 per row, one chunk per thread
    {
        int r = tid >> 2, q = tid & 3;
        uint4 a = *(const uint4*)&remb[(size_t)(g0 + r) * 32 + q * 8];
        uint4 b = *(const uint4*)&temb[(size_t)(g0 + r) * 32 + q * 8];
        __bf16* p = &cb[r * 136 + 44 + q * 8];
        *(uint2*)p       = make_uint2(a.x, a.y);
        *(uint2*)(p + 4) = make_uint2(a.z, a.w);
        __bf16* p2 = &cb[r * 136 + 76 + q * 8];
        *(uint2*)p2       = make_uint2(b.x, b.y);
        *(uint2*)(p2 + 4) = make_uint2(b.z, b.w);
    }
    // zero pad k in [108,128): 5 x uint2 per row
    for (int i = tid; i < 64 * 5; i += 256) {
        int r = i / 5, c = i - r * 5;
        *(uint2*)&cb[r * 136 + 108 + c * 4] = make_uint2(0u, 0u);
    }
    __syncthreads();

    bf16x8 cf[4];
#pragma unroll
    for (int kq = 0; kq < 4; ++kq)
        cf[kq] = ld_frag(&cb[(w * 16 + ln) * 136 + kq * 32 + qd * 8]);
    floatx4 acc1[8];
#pragma unroll
    for (int mt = 0; mt < 8; ++mt) {
        float4 bv = *(const float4*)&b1[mt * 16 + qd * 4];
        floatx4 acc = (floatx4){bv.x, bv.y, bv.z, bv.w};
#pragma unroll
        for (int kq = 0; kq < 4; ++kq) {
            bf16x8 af = ld_frag(&hw1[(mt * 16 + ln) * 128 + kq * 32 + qd * 8]);
            acc = __builtin_amdgcn_mfma_f32_16x16x32_bf16(af, cf[kq], acc, 0, 0, 0);
        }
        acc1[mt] = acc;
    }
    bf16x8 f1[4];
#pragma unroll
    for (int kq = 0; kq < 4; ++kq)
        f1[kq] = pack_relu2(acc1[2 * kq], acc1[2 * kq + 1]);

    floatx4 acc2[8];
#pragma unroll
    for (int mt = 0; mt < 8; ++mt) {
        float4 bv = *(const float4*)&b2[mt * 16 + qd * 4];
        floatx4 acc = (floatx4){bv.x, bv.y, bv.z, bv.w};
#pragma unroll
        for (int kq = 0; kq < 4; ++kq) {
            bf16x8 af = ld_frag(&hw2[(mt * 16 + ln) * 128 + kq * 32 + qd * 8]);
            acc = __builtin_amdgcn_mfma_f32_16x16x32_bf16(af, f1[kq], acc, 0, 0, 0);
        }
        acc2[mt] = acc;
    }
    bf16x8 f2[4];
#pragma unroll
    for (int kq = 0; kq < 4; ++kq)
        f2[kq] = pack_relu2(acc2[2 * kq], acc2[2 * kq + 1]);

    floatx4 acc3[4];
#pragma unroll
    for (int mt = 0; mt < 4; ++mt) {
        float4 bv = *(const float4*)&b3[mt * 16 + qd * 4];
        floatx4 acc = (floatx4){bv.x, bv.y, bv.z, bv.w};
#pragma unroll
        for (int kq = 0; kq < 4; ++kq) {
            bf16x8 af = ld_frag(&hw3[(mt * 16 + ln) * 128 + kq * 32 + qd * 8]);
            acc = __builtin_amdgcn_mfma_f32_16x16x32_bf16(af, f2[kq], acc, 0, 0, 0);
        }
        acc3[mt] = acc;
    }

    float part = 0.0f;
#pragma unroll
    for (int mt = 0; mt < 4; ++mt) {
        float4 wv = *(const float4*)&w4[mt * 16 + qd * 4];
        part = fmaf(fmaxf(acc3[mt][0], 0.0f), wv.x, part);
        part = fmaf(fmaxf(acc3[mt][1], 0.0f), wv.y, part);
        part = fmaf(fmaxf(acc3[mt][2], 0.0f), wv.z, part);
        part = fmaf(fmaxf(acc3[mt][3], 0.0f), wv.w, part);
    }
    part += __shfl_xor(part, 16);
    part += __shfl_xor(part, 32);
    if (qd == 0)
        out[g0 + w * 16 + ln] = part + b4[0];
}

extern "C" void kernel_launch(void* const* d_in, const int* in_sizes, int n_in,
                              void* d_out, int out_size, void* d_ws, size_t ws_size,
                              hipStream_t stream)
{
    const float* t0  = (const float*)d_in[0];
    const float* rX  = (const float*)d_in[1];
    const float* tX  = (const float*)d_in[2];
    const float* rw1 = (const float*)d_in[3];  const float* rb1 = (const float*)d_in[4];
    const float* rw2 = (const float*)d_in[5];  const float* rb2 = (const float*)d_in[6];
    const float* rw3 = (const float*)d_in[7];  const float* rb3 = (const float*)d_in[8];
    const float* tw1 = (const float*)d_in[9];  const float* tb1 = (const float*)d_in[10];
    const float* tw2 = (const float*)d_in[11]; const float* tb2 = (const float*)d_in[12];
    const float* tw3 = (const float*)d_in[13]; const float* tb3 = (const float*)d_in[14];
    const float* mw1 = (const float*)d_in[15]; const float* mb1 = (const float*)d_in[16];
    const float* mw2 = (const float*)d_in[17]; const float* mb2 = (const float*)d_in[18];
    const float* mw3 = (const float*)d_in[19]; const float* mb3 = (const float*)d_in[20];
    const float* mw4 = (const float*)d_in[21]; const float* mb4 = (const float*)d_in[22];
    float* out = (float*)d_out;

    const int B = 16384;
    __bf16* remb = (__bf16*)d_ws;
    __bf16* temb = (__bf16*)((char*)d_ws + ((size_t)1 << 20));
    __bf16* wb   = (__bf16*)((char*)d_ws + ((size_t)2 << 20));
    const __bf16* mw1b = wb + 16384; const __bf16* mw2b = wb + 32768;
    const __bf16* mw3b = wb + 49152;

    prep_kernel<<<64, 256, 0, stream>>>(rw1, rb1, rw2, rw3, tw1, tb1, tw2, tw3,
                                        mw1, mw2, mw3, wb);
    enc_fused<<<3072, 256, 0, stream>>>(rX, tX, wb,
                                        rb2, rb3, tb2, tb3,
                                        remb, temb);
    head_mfma<<<B / 64, 256, 0, stream>>>(t0, remb, temb,
                                          mw1b, mb1, mw2b, mb2, mw3b, mb3,
                                          mw4, mb4, out);
}